// Round 7
// baseline (182.448 us; speedup 1.0000x reference)
//
#include <hip/hip_runtime.h>
#include <hip/hip_bf16.h>

typedef __bf16 bf16;
typedef __bf16 bf16x8 __attribute__((ext_vector_type(8)));
typedef __bf16 bf16x4 __attribute__((ext_vector_type(4)));
typedef __bf16 bf16x2 __attribute__((ext_vector_type(2)));
typedef float f32x4 __attribute__((ext_vector_type(4)));

static __device__ __forceinline__ f32x4 mfma16(bf16x8 a, bf16x8 b, f32x4 c) {
    return __builtin_amdgcn_mfma_f32_16x16x32_bf16(a, b, c, 0, 0, 0);
}

static __device__ __forceinline__ void load16_to_lds(const void* g, void* l) {
    __builtin_amdgcn_global_load_lds(
        (const __attribute__((address_space(1))) unsigned int*)g,
        (__attribute__((address_space(3))) unsigned int*)l, 16, 0, 0);
}

#define LKV 2048
#define DM 256

// ================= shared GEMM body: Y[64 x 256] = X * W^T, W read as f32 =================
template<bool IN_BF16, bool OUT_BF16, bool HAS_BIAS>
static __device__ __forceinline__ void gemm_body(char* smem,
                                                 const void* __restrict__ Xv,
                                                 const float* __restrict__ Wf,
                                                 const float* __restrict__ bias,
                                                 float scale, void* __restrict__ Y,
                                                 long rowbase) {
    bf16* Xl  = (bf16*)smem;            // [64][264] bf16 (528B rows)
    char* WlB = smem + 33792;           // [256][40] bf16 (80B rows)
    const int tid  = threadIdx.x;
    const int lane = tid & 63, wave = tid >> 6;
    const int hi = lane >> 4, lo = lane & 15;

    if (IN_BF16) {
        const bf16* Xb = (const bf16*)Xv;
#pragma unroll
        for (int i = 0; i < 8; ++i) {
            int idx = i * 256 + tid;
            int r = idx >> 5, c8 = (idx & 31) * 8;
            uint4 v = *(const uint4*)(Xb + (rowbase + r) * 256 + c8);
            *(uint4*)(Xl + r * 264 + c8) = v;
        }
    } else {
        const float* X = (const float*)Xv;
#pragma unroll
        for (int i = 0; i < 16; ++i) {
            int idx4 = i * 256 + tid;
            int e = idx4 * 4;
            int r = e >> 8, c = e & 255;
            float4 v = *(const float4*)(X + (rowbase + r) * 256 + c);
            bf16x4 o;
            o[0] = (bf16)v.x; o[1] = (bf16)v.y; o[2] = (bf16)v.z; o[3] = (bf16)v.w;
            *(bf16x4*)(Xl + r * 264 + c) = o;
        }
    }

    f32x4 acc[16];
    const f32x4 zero = {0.f, 0.f, 0.f, 0.f};
#pragma unroll
    for (int n = 0; n < 16; ++n) acc[n] = zero;

    for (int ks = 0; ks < 8; ++ks) {
        __syncthreads();
        // stage W[e][ks*32..+31] f32 -> bf16 Wl
#pragma unroll
        for (int c = 0; c < 8; ++c) {
            int idx = c * 256 + tid;            // 2048 float4 chunks
            int e = idx >> 3, q4 = (idx & 7) * 4;
            float4 v = *(const float4*)(Wf + e * 256 + ks * 32 + q4);
            bf16x4 o;
            o[0] = (bf16)v.x; o[1] = (bf16)v.y; o[2] = (bf16)v.z; o[3] = (bf16)v.w;
            *(bf16x4*)(WlB + e * 80 + q4 * 2) = o;
        }
        __syncthreads();
        bf16x8 a = *(const bf16x8*)((const char*)Xl + (wave * 16 + lo) * 528 + ks * 64 + hi * 16);
#pragma unroll
        for (int n = 0; n < 16; ++n) {
            bf16x8 bfr = *(const bf16x8*)(WlB + (n * 16 + lo) * 80 + hi * 16);
            acc[n] = mfma16(a, bfr, acc[n]);
        }
    }

#pragma unroll
    for (int n = 0; n < 16; ++n) {
        int col = n * 16 + lo;
        float bv = HAS_BIAS ? bias[col] : 0.f;
#pragma unroll
        for (int r = 0; r < 4; ++r) {
            long row = rowbase + wave * 16 + hi * 4 + r;
            float v = acc[n][r] * scale + bv;
            if (OUT_BF16) ((bf16*)Y)[row * 256 + col] = (bf16)v;
            else          ((float*)Y)[row * 256 + col] = v;
        }
    }
}

// ================= prep_qk: blocks [0,1024) = q/k projection; [1024,3072) = tsp -> tspF ======
// tspF frag layout: byte addr = b*1MB + ((t*16 + dt)*64 + lane)*16,
// holding tspT[d = dt*16 + (lane&15)][kv = t*32 + (lane>>4)*8 .. +7] as bf16x8.
__global__ __launch_bounds__(256) void prep_qk(const float* __restrict__ q,
                                               const float* __restrict__ k,
                                               const float* __restrict__ wqk,
                                               const float* __restrict__ tsp,
                                               bf16* __restrict__ qp,
                                               bf16* __restrict__ kp,
                                               bf16* __restrict__ tspF) {
    __shared__ __align__(16) char smem[54272];
    const int tid = threadIdx.x;
    int bid = (int)blockIdx.x;
    if (bid < 1024) {
        bool is_k = bid >= 512;
        gemm_body<false, true, false>(smem, is_k ? k : q, wqk, nullptr,
                                      is_k ? 1.0f : 0.0625f, is_k ? kp : qp,
                                      (long)(bid & 511) * 64);
        return;
    }
    // transpose path
    int id = bid - 1024;                       // 2048 tiles: 16 b x 32 kv-tiles x 4 d-tiles
    const int b = id >> 7;
    const int kv0 = (id & 31) * 64, d0 = ((id >> 5) & 3) * 64;
    float (*tile)[65] = (float(*)[65])smem;
#pragma unroll
    for (int i = 0; i < 4; ++i) {
        int idx = i * 256 + tid;
        int kv = idx >> 4, c4 = (idx & 15) * 4;
        float4 v = *(const float4*)(tsp + ((long)(b * LKV + kv0 + kv)) * DM + d0 + c4);
        tile[kv][c4 + 0] = v.x; tile[kv][c4 + 1] = v.y;
        tile[kv][c4 + 2] = v.z; tile[kv][c4 + 3] = v.w;
    }
    __syncthreads();
    char* outb = (char*)tspF + ((long)b << 20);
#pragma unroll
    for (int i = 0; i < 2; ++i) {
        int w = i * 256 + tid;                  // 512 frag-words
        int ti = w >> 8;                        // 0..1 (== i)
        int dti = (w >> 6) & 3;
        int lane = w & 63;
        int hi = lane >> 4, lo = lane & 15;
        bf16x8 o;
#pragma unroll
        for (int j = 0; j < 8; ++j) o[j] = (bf16)tile[ti * 32 + hi * 8 + j][dti * 16 + lo];
        int t_abs = (kv0 >> 5) + ti;
        int dt_abs = (d0 >> 4) + dti;
        *(bf16x8*)(outb + (((t_abs * 16 + dt_abs) << 6) + lane) * 16) = o;
    }
}

// ================= gemm_out: out = gated(bf16) @ w1^T + b1, f32 out ==========================
__global__ __launch_bounds__(256) void gemm_out(const bf16* __restrict__ gated,
                                                const float* __restrict__ w1,
                                                const float* __restrict__ b1,
                                                float* __restrict__ out) {
    __shared__ __align__(16) char smem[54272];
    gemm_body<true, false, true>(smem, gated, w1, b1, 1.0f, out, (long)blockIdx.x * 64);
}

// ================= flash v6: kp in LDS (3-slot, 1 barrier/phase), tsp frags global->reg ======
// grid = 512 XCD-swizzled, block = 256 (4 waves, lane owns q = lane&15). KV tile = 32.
// Phase t: vmcnt(N) -> barrier -> [tfrag(t) x16 loads, DMA kp(t+2) x4] -> QK(t) -> softmax(t)
//          -> PV(t) (register-only MFMA).
__global__ __launch_bounds__(256, 2) void flash6(const bf16* __restrict__ qp,
                                                 const bf16* __restrict__ kp,
                                                 const bf16* __restrict__ tspF,
                                                 const float* __restrict__ qorig,
                                                 bf16* __restrict__ gated) {
    __shared__ __align__(16) char kbuf[3][16384];   // [kv][512B], chunk i ^= (kv&7)
    const int tid  = threadIdx.x;
    const int lane = tid & 63, wave = tid >> 6;
    const int hi = lane >> 4, lo = lane & 15;

    int id  = (int)blockIdx.x;
    int bid = (id & 7) * 64 + (id >> 3);
    const int b  = bid >> 5;
    const int qb = bid & 31;
    const long qbase = (long)b * LKV + qb * 64;
    const char* kp_g  = (const char*)(kp + (long)b * LKV * DM);
    const char* tsp_f = (const char*)tspF + ((long)b << 20) + lane * 16;

    // per-lane inverse-swizzled source offsets for kp DMA
    int kp_off[4];
#pragma unroll
    for (int j = 0; j < 4; ++j) {
        int kv = wave * 8 + j * 2 + (lane >> 5);
        kp_off[j] = kv * 512 + (((lane & 31) ^ (kv & 7)) << 4);
    }

    // bpermute source addrs: slot k fetches from lane (2*(hi&1)+(k>>1))*16 + lo
    int bp_src[4];
#pragma unroll
    for (int k2 = 0; k2 < 4; ++k2)
        bp_src[k2] = ((((hi & 1) * 2 + (k2 >> 1)) << 4) + lo) << 2;

    // q fragments: lane's q-row is lo
    bf16x8 aq[8];
    {
        const bf16* qrow = qp + (qbase + wave * 16 + lo) * DM;
#pragma unroll
        for (int ks = 0; ks < 8; ++ks) aq[ks] = *(const bf16x8*)(qrow + ks * 32 + hi * 8);
    }

    bf16x8 ones;
#pragma unroll
    for (int j = 0; j < 8; ++j) ones[j] = (bf16)1.0f;

    f32x4 o[16], o_l;
    const f32x4 zero = {0.f, 0.f, 0.f, 0.f};
#pragma unroll
    for (int n = 0; n < 16; ++n) o[n] = zero;
    o_l = zero;
    float m = -1e30f, tm = -1e30f;

    const int kswz = (lo & 7) << 4;

    // prologue: DMA kp tiles 0,1 into slots 0,1
#pragma unroll
    for (int j = 0; j < 4; ++j)
        load16_to_lds(kp_g + kp_off[j],          &kbuf[0][wave * 4096 + j * 1024]);
#pragma unroll
    for (int j = 0; j < 4; ++j)
        load16_to_lds(kp_g + 16384 + kp_off[j],  &kbuf[1][wave * 4096 + j * 1024]);

    for (int t = 0; t < 64; ++t) {
        if (t == 0)       { asm volatile("s_waitcnt vmcnt(4)"  ::: "memory"); }
        else if (t == 63) { asm volatile("s_waitcnt vmcnt(16)" ::: "memory"); }
        else              { asm volatile("s_waitcnt vmcnt(20)" ::: "memory"); }
        __builtin_amdgcn_sched_barrier(0);
        __builtin_amdgcn_s_barrier();
        __builtin_amdgcn_sched_barrier(0);

        // ---- issue: tsp frags for tile t (16 x 1KB, identical across waves -> L1 broadcast),
        //      then kp DMA for tile t+2 into slot (t+2)%3 ----
        bf16x8 tt[16];
        {
            const char* tb = tsp_f + (long)t * 16384;
#pragma unroll
            for (int dt = 0; dt < 16; ++dt)
                tt[dt] = *(const bf16x8*)(tb + dt * 1024);
        }
        if (t < 62) {
            const int dslot = (t + 2) % 3;
            const char* src = kp_g + (long)(t + 2) * 16384;
#pragma unroll
            for (int j = 0; j < 4; ++j)
                load16_to_lds(src + kp_off[j], &kbuf[dslot][wave * 4096 + j * 1024]);
        }
        __builtin_amdgcn_sched_barrier(0);

        // ---- QK(t): S^T[kv][q] = mfma(K,Q); lane: q=lo, kv = n*16 + 4*hi + r ----
        f32x4 s[2];
        const char* kb = kbuf[t % 3];
        __builtin_amdgcn_s_setprio(1);
#pragma unroll
        for (int n = 0; n < 2; ++n) {
            s[n] = zero;
            const char* rowp = kb + ((n * 16 + lo) << 9);
#pragma unroll
            for (int ks = 0; ks < 8; ++ks) {
                bf16x8 kk = *(const bf16x8*)(rowp + ((ks * 64 + hi * 16) ^ kswz));
                s[n] = mfma16(kk, aq[ks], s[n]);
            }
        }
        __builtin_amdgcn_s_setprio(0);

        // ---- softmax(t): per-lane for q=lo ----
        float pm = fmaxf(fmaxf(fmaxf(s[0][0], s[0][1]), fmaxf(s[0][2], s[0][3])),
                         fmaxf(fmaxf(s[1][0], s[1][1]), fmaxf(s[1][2], s[1][3])));
        pm = fmaxf(pm, __shfl_xor(pm, 16));
        pm = fmaxf(pm, __shfl_xor(pm, 32));
        tm = fmaxf(tm, pm);
        if (__any(pm > m + 8.f)) {       // defer-max THR=8
            float nm = fmaxf(m, pm);
            float a = __expf(m - nm);
            m = nm;
            o_l *= a;
#pragma unroll
            for (int n = 0; n < 16; ++n) o[n] *= a;
        }
        int cvt[2][2];
#pragma unroll
        for (int n = 0; n < 2; ++n)
#pragma unroll
            for (int c = 0; c < 2; ++c) {
                bf16x2 pr;
                pr[0] = (bf16)__expf(s[n][2 * c]     - m);
                pr[1] = (bf16)__expf(s[n][2 * c + 1] - m);
                cvt[n][c] = __builtin_bit_cast(int, pr);
            }
        int pki[4];
#pragma unroll
        for (int k2 = 0; k2 < 4; ++k2) {
            int a0 = __builtin_amdgcn_ds_bpermute(bp_src[k2], cvt[0][k2 & 1]);
            int a1 = __builtin_amdgcn_ds_bpermute(bp_src[k2], cvt[1][k2 & 1]);
            pki[k2] = (hi < 2) ? a0 : a1;
        }
        int4 pii = make_int4(pki[0], pki[1], pki[2], pki[3]);
        bf16x8 pk = __builtin_bit_cast(bf16x8, pii);   // P[q=lo][kv = 8*hi + j]

        // ---- PV(t): register-only MFMAs; O^T[d][q] += tspF_frag * P ----
        o_l = mfma16(ones, pk, o_l);
        __builtin_amdgcn_s_setprio(1);
#pragma unroll
        for (int dt = 0; dt < 16; ++dt)
            o[dt] = mfma16(tt[dt], pk, o[dt]);
        __builtin_amdgcn_s_setprio(0);
    }

    // ---- epilogue: lane owns q-row lo; d = dt*16 + 4*hi + r ----
    float prob = 1.f / (1.f + __expf(-tm));
    float invl = 1.f / o_l[0];
    long row = qbase + wave * 16 + lo;
#pragma unroll
    for (int dt = 0; dt < 16; ++dt) {
        int c0 = dt * 16 + hi * 4;
        float4 qv = *(const float4*)(qorig + row * 256 + c0);
        bf16x4 g;
        g[0] = (bf16)((qv.x + o[dt][0] * invl) * prob);
        g[1] = (bf16)((qv.y + o[dt][1] * invl) * prob);
        g[2] = (bf16)((qv.z + o[dt][2] * invl) * prob);
        g[3] = (bf16)((qv.w + o[dt][3] * invl) * prob);
        *(bf16x4*)(gated + row * 256 + c0) = g;
    }
}

extern "C" void kernel_launch(void* const* d_in, const int* in_sizes, int n_in,
                              void* d_out, int out_size, void* d_ws, size_t ws_size,
                              hipStream_t stream) {
    const float* q    = (const float*)d_in[0];
    const float* k    = (const float*)d_in[1];
    const float* tsp  = (const float*)d_in[2];
    const float* w_qk = (const float*)d_in[3];
    const float* w1   = (const float*)d_in[4];
    const float* b1   = (const float*)d_in[5];
    float* out = (float*)d_out;
    char* ws = (char*)d_ws;

    bf16* qp_b  = (bf16*)(ws + 0);           // 16 MB
    bf16* kp_b  = (bf16*)(ws + 16777216);    // 16 MB
    bf16* tspF  = (bf16*)(ws + 33554432);    // 16 MB (frag layout)
    bf16* gated = (bf16*)(ws + 50331648);    // 16 MB

    prep_qk<<<3072, 256, 0, stream>>>(q, k, w_qk, tsp, qp_b, kp_b, tspF);

    flash6<<<512, 256, 0, stream>>>(qp_b, kp_b, tspF, q, gated);

    gemm_out<<<512, 256, 0, stream>>>(gated, w1, b1, out);
}